// Round 6
// baseline (197.471 us; speedup 1.0000x reference)
//
#include <hip/hip_runtime.h>
#include <hip/hip_bf16.h>
#include <stdint.h>

// y[c,k] = sum_{a,b} E1[k,a] * Xc[c,a,b] * E2[k,b],  Xc = C*x, E = exp(i*angle*g)
//
// R6 = R5's folded GEMM (M=512, K=257 pad 320, N=64/block) with the LDS
// waste removed:
//  - A-tile rows are WAVE-EXCLUSIVE (wave w owns rows w*128..+127): staging
//    them through LDS had zero sharing -> A fragments now load DIRECT from
//    global (L2-resident, same VMEM bytes as the old gload_lds path, minus
//    the 128KB/block-tile LDS round trip). LDS traffic/block-tile 168->40KB.
//  - vmcnt ordering (R2's lesson, fixed by construction): per tile issue all
//    16 af global loads FIRST, then the 2 B gload_lds, fenced by
//    sched_barrier(0). Waiting on af = vmcnt(2) (B stages newest, stay in
//    flight); the only vmcnt(0) is the tile-end __syncthreads, issued ~16
//    loads + 64 MFMAs later.
//  - R4's spill trap: no persistent reg dbuf; af[2][8] lives within one tile;
//    "#pragma unroll 1" stops cross-tile load hoisting. ~233 regs peak @ (256,2).
//  - B (the only shared operand, 4x reuse) stays in LDS, double-buffered
//    2x8KB, chunk-XOR swizzle (conflicts were 0 through R0-R5).
//  - pack_a + pack_be fused into one kernel (one less launch boundary).

#define NKTOT 17408
#define NBLK 272    // ktiles of 64 k-values
#define LDK 320     // padded K (257 -> 320 = 5 x 64)

typedef short bf16x8 __attribute__((ext_vector_type(8)));
typedef float f32x4 __attribute__((ext_vector_type(4)));

__device__ __forceinline__ unsigned short f2bf(float f) {
  unsigned int u = __builtin_bit_cast(unsigned int, f);
  u += 0x7FFFu + ((u >> 16) & 1u);
  return (unsigned short)(u >> 16);
}
__device__ __forceinline__ float bf2f(unsigned int lo16) {
  return __builtin_bit_cast(float, lo16 << 16);
}

__device__ __forceinline__ void async_copy16(void* lds, const void* g) {
  __builtin_amdgcn_global_load_lds(
      (const __attribute__((address_space(1))) unsigned int*)g,
      (__attribute__((address_space(3))) unsigned int*)lds, 16, 0, 0);
}

// Fused packing. Blocks 0..1023: fold A (2 (c,a) rows per block).
// Blocks 1024..18431: one k each -> B row (cos|sin) + E1 row.
__global__ __launch_bounds__(256) void pack_all(
    const float* __restrict__ input_r, const float* __restrict__ C_r,
    const float* __restrict__ angle,
    unsigned short* __restrict__ Apack, unsigned short* __restrict__ BT,
    unsigned int* __restrict__ E1tab)
{
  const int bx = blockIdx.x;
  const int tid = threadIdx.x;
  if (bx < 1024) {
    //   XcC[j] = Xc[128+j]+Xc[128-j] (j=1..127), XcC[0]=Xc[128], XcC[128]=Xc[0]
    //   XcS[j] = Xc[128+j]-Xc[128-j] (j=1..127), XcS[128]=-Xc[0]
    //   A_re = [Re XcC | -Im XcS] rows 0..255 ; A_im = [Im XcC | Re XcS] 256..511
    const int p = bx * 2 + (tid >> 7);   // (c,a) pair index 0..2047
    const int a = p & 255;
    const int c = p >> 8;
    const int j = tid & 127;
    const size_t xbase = (size_t)a * 256;
    const size_t cbase = ((size_t)(c * 256 + a)) * 256;
    unsigned short* Ar = Apack + ((size_t)c * 512 + a) * LDK;
    unsigned short* Ai = Apack + ((size_t)c * 512 + 256 + a) * LDK;
    if (j == 0) {
      float xr = input_r[(xbase + 128) * 2], xi = input_r[(xbase + 128) * 2 + 1];
      float cr = C_r[(cbase + 128) * 2],     ci = C_r[(cbase + 128) * 2 + 1];
      Ar[0] = f2bf(cr * xr - ci * xi);
      Ai[0] = f2bf(cr * xi + ci * xr);
      xr = input_r[xbase * 2]; xi = input_r[xbase * 2 + 1];
      cr = C_r[cbase * 2];     ci = C_r[cbase * 2 + 1];
      float reb = cr * xr - ci * xi, imb = cr * xi + ci * xr;
      Ar[128] = f2bf(reb);  Ai[128] = f2bf(imb);   // XcC[128] = Xc(b=0)
      Ar[256] = f2bf(imb);                         // -Im(XcS[128])
      Ai[256] = f2bf(-reb);                        //  Re(XcS[128])
    } else {
      const int bp = 128 + j, bm = 128 - j;
      float xpr = input_r[(xbase + bp) * 2], xpi = input_r[(xbase + bp) * 2 + 1];
      float cpr = C_r[(cbase + bp) * 2],     cpi = C_r[(cbase + bp) * 2 + 1];
      float pr = cpr * xpr - cpi * xpi, pi = cpr * xpi + cpi * xpr;
      float xmr = input_r[(xbase + bm) * 2], xmi = input_r[(xbase + bm) * 2 + 1];
      float cmr = C_r[(cbase + bm) * 2],     cmi = C_r[(cbase + bm) * 2 + 1];
      float mr = cmr * xmr - cmi * xmi, mi = cmr * xmi + cmi * xmr;
      Ar[j]       = f2bf(pr + mr);        //  Re XcC
      Ai[j]       = f2bf(pi + mi);        //  Im XcC
      Ar[128 + j] = f2bf(mi - pi);        // -Im XcS
      Ai[128 + j] = f2bf(pr - mr);        //  Re XcS
    }
    if (j < 63) {  // zero-pad cols 257..319
      Ar[257 + j] = 0;
      Ai[257 + j] = 0;
    }
  } else {
    const int k = bx - 1024;             // 0..17407
    const float s = angle[k * 2 + 0];
    const float t = angle[k * 2 + 1];
    float sn, cs;
    __sincosf(s * (float)(tid - 128), &sn, &cs);   // E1[k, a=tid]
    E1tab[(size_t)k * 256 + tid] =
        (unsigned int)f2bf(cs) | ((unsigned int)f2bf(sn) << 16);
    unsigned short* Brow = BT + (size_t)k * LDK;
    if (tid <= 128) {
      __sincosf(t * (float)tid, &sn, &cs);
      Brow[tid] = f2bf(cs);
      if (tid >= 1) Brow[128 + tid] = f2bf(sn);
    } else if (tid < 192) {
      Brow[128 + tid] = 0;   // cols 257..319
    }
  }
}

__global__ __launch_bounds__(256, 2) void gemm_fused(
    const unsigned short* __restrict__ Apack,
    const unsigned short* __restrict__ BT,
    const unsigned int* __restrict__ E1tab,
    const float* __restrict__ wvec,
    float* __restrict__ out)
{
  __shared__ unsigned short Bs[2][64 * 64];  // 2 x 8 KB B double-buffer
  __shared__ float scol[4][2][64];           // 2 KB
  // 18 KB total -> LDS never limits; 2 blocks/CU from the (256,2) reg cap.

  // XCD-aware decode: bx%8 == ktile%8 keeps all 8 c-blocks of one ktile on
  // the same XCD. 2176 = 34*64 -> bijective.
  const int bx = blockIdx.x;
  const int c = (bx >> 3) & 7;
  const int ktile = (bx >> 6) * 8 + (bx & 7);   // 0..271
  const int kt0 = ktile * 64;
  const int tid = threadIdx.x;
  const int w = tid >> 6;       // 0..3: owns A rows w*128..w*128+127
  const int l = tid & 63;
  const int lhi = l >> 4;       // 0..3
  const int llo = l & 15;
  const int lr = l >> 3;                      // staging: row within 8-row chunk
  const int lcs = ((l & 7) ^ lr) * 8;         // staging: swizzled source chunk

  const unsigned short* Bbase = BT + (size_t)kt0 * LDK;
  // Per-lane A fragment base: af[kf][fi] = A[w*128 + fi*16 + llo]
  //                                         [kk + kf*32 + lhi*8 .. +7]
  // (identical algebra to the old LDS path: slot^(row&7) collapses to
  //  kf*32 + lhi*8 since row&7 == llo&7). 16B aligned, 64B segments, L2-hot.
  const unsigned short* Arow = Apack + ((size_t)c * 512 + w * 128 + llo) * LDK
                             + lhi * 8;

  const int sl0 = lhi ^ (llo & 7);   // B LDS slot base (kf=0); kf=1 -> sl0^4

  f32x4 acc[8][4];
#pragma unroll
  for (int i = 0; i < 8; ++i)
#pragma unroll
    for (int j = 0; j < 4; ++j) {
      f32x4 z = {0.f, 0.f, 0.f, 0.f};
      acc[i][j] = z;
    }

  // Prologue: stage B tile 0 (8 chunks of 8 rows; wave w does 2)
#pragma unroll
  for (int i = 0; i < 2; ++i) {
    int row0 = (w * 2 + i) * 8;
    async_copy16(&Bs[0][row0 * 64], Bbase + (size_t)(row0 + lr) * LDK + lcs);
  }
  __syncthreads();

#pragma unroll 1   // no cross-tile hoisting of global loads (R4's spill trap)
  for (int tt = 0; tt < 5; ++tt) {
    const int kk = tt * 64;
    const int cu = tt & 1;
    const unsigned short* Bc = &Bs[cu][0];

    // (1) A fragments for BOTH kf, direct from global — issued FIRST so the
    //     MFMA wait is a counted vmcnt (B stages below stay in flight).
    bf16x8 af0[8], af1[8];
#pragma unroll
    for (int fi = 0; fi < 8; ++fi)
      af0[fi] = *(const bf16x8*)(Arow + (size_t)fi * 16 * LDK + kk);
#pragma unroll
    for (int fi = 0; fi < 8; ++fi)
      af1[fi] = *(const bf16x8*)(Arow + (size_t)fi * 16 * LDK + kk + 32);
    __builtin_amdgcn_sched_barrier(0);   // af loads stay above B staging

    // (2) stage next B tile into the other buffer (2 gload_lds, newest vmem)
    if (tt < 4) {
#pragma unroll
      for (int i = 0; i < 2; ++i) {
        int row0 = (w * 2 + i) * 8;
        async_copy16(&Bs[cu ^ 1][row0 * 64],
                     Bbase + (size_t)(row0 + lr) * LDK + kk + 64 + lcs);
      }
    }
    __builtin_amdgcn_sched_barrier(0);   // staging stays above compute

    // (3) compute: kf0 then kf1; af waits are vmcnt(10)/vmcnt(2)
    {
      const int soff = sl0 * 8;
      bf16x8 bfr[4];
#pragma unroll
      for (int fj = 0; fj < 4; ++fj)
        bfr[fj] = *(const bf16x8*)&Bc[(fj * 16 + llo) * 64 + soff];
#pragma unroll
      for (int fi = 0; fi < 8; ++fi)
#pragma unroll
        for (int fj = 0; fj < 4; ++fj)
          acc[fi][fj] = __builtin_amdgcn_mfma_f32_16x16x32_bf16(
              af0[fi], bfr[fj], acc[fi][fj], 0, 0, 0);
    }
    {
      const int soff = (sl0 ^ 4) * 8;
      bf16x8 bfr[4];
#pragma unroll
      for (int fj = 0; fj < 4; ++fj)
        bfr[fj] = *(const bf16x8*)&Bc[(fj * 16 + llo) * 64 + soff];
#pragma unroll
      for (int fi = 0; fi < 8; ++fi)
#pragma unroll
        for (int fj = 0; fj < 4; ++fj)
          acc[fi][fj] = __builtin_amdgcn_mfma_f32_16x16x32_bf16(
              af1[fi], bfr[fj], acc[fi][fj], 0, 0, 0);
    }
    // Tile end: the ONLY vmcnt(0) — B stages are ~16 loads + 64 MFMAs old.
    __syncthreads();
  }

  // Epilogue: wave w holds T rows (w<2: Tr, w>=2: Ti), a-half = (w&1)*128.
  // Per col: S_r = sum E1r*v, S_i = sum E1i*v over this wave's 128 rows.
  const int ahalf = (w & 1) * 128;
#pragma unroll
  for (int fj = 0; fj < 4; ++fj) {
    const int col = fj * 16 + llo;
    const int k = kt0 + col;
    float sumr = 0.f, sumi = 0.f;
    const unsigned int* e1base = E1tab + (size_t)k * 256 + ahalf + lhi * 4;
#pragma unroll
    for (int fi = 0; fi < 8; ++fi) {
      uint4 e4 = *(const uint4*)(e1base + fi * 16);
      unsigned int ev[4] = {e4.x, e4.y, e4.z, e4.w};
#pragma unroll
      for (int r = 0; r < 4; ++r) {
        float v = acc[fi][fj][r];     // T at (a = ahalf + fi*16 + lhi*4 + r, k)
        sumr += bf2f(ev[r] & 0xFFFFu) * v;
        sumi += bf2f(ev[r] >> 16) * v;
      }
    }
    sumr += __shfl_xor(sumr, 16, 64);
    sumr += __shfl_xor(sumr, 32, 64);
    sumi += __shfl_xor(sumi, 16, 64);
    sumi += __shfl_xor(sumi, 32, 64);
    if (lhi == 0) {
      scol[w][0][col] = sumr;
      scol[w][1][col] = sumi;
    }
  }
  __syncthreads();
  if (tid < 128) {
    const int col = tid >> 1;
    const int comp = tid & 1;
    const int k = kt0 + col;
    // Re = S_rr(0)+S_rr(1) - S_ii(2)-S_ii(3) ; Im = S_ri(0)+S_ri(1) + S_ir(2)+S_ir(3)
    float re = scol[0][0][col] + scol[1][0][col]
             - scol[2][1][col] - scol[3][1][col];
    float im = scol[0][1][col] + scol[1][1][col]
             + scol[2][0][col] + scol[3][0][col];
    float val = comp ? im : re;
    out[((size_t)c * NKTOT + k) * 2 + comp] = val * wvec[k & 511];
  }
}

extern "C" void kernel_launch(void* const* d_in, const int* in_sizes, int n_in,
                              void* d_out, int out_size, void* d_ws, size_t ws_size,
                              hipStream_t stream) {
  const float* input_r = (const float*)d_in[0];  // (256,256,2)
  const float* C_r     = (const float*)d_in[1];  // (8,256,256,2)
  const float* wvec    = (const float*)d_in[2];  // (512,)
  const float* angle   = (const float*)d_in[3];  // (17408,2)
  float* out = (float*)d_out;                    // (8,17408,2)

  // workspace: A'' 8*512*320*2 = 2.62MB | BT 17408*320*2 = 11.1MB |
  //            E1tab 17408*256*4 = 17.8MB  => ~31.6MB
  unsigned short* Apack = (unsigned short*)d_ws;
  unsigned short* BT    = (unsigned short*)((char*)d_ws + (size_t)2621440);
  unsigned int*   E1tab = (unsigned int*)((char*)d_ws + (size_t)2621440 + 11141120);

  pack_all<<<1024 + NKTOT, 256, 0, stream>>>(input_r, C_r, angle,
                                             Apack, BT, E1tab);
  gemm_fused<<<8 * NBLK, 256, 0, stream>>>(Apack, BT, E1tab, wvec, out);
}

// Round 7
// 139.704 us; speedup vs baseline: 1.4135x; 1.4135x over previous
//
#include <hip/hip_runtime.h>
#include <hip/hip_bf16.h>
#include <stdint.h>

// y[c,k] = sum_{a,b} E1[k,a] * Xc[c,a,b] * E2[k,b],  Xc = C*x, E = exp(i*angle*g)
//
// R7 = R5's folded GEMM (M=512, K=257->288, N=64/block) + double-buffered
// staging at BK=32 so the per-tile vmcnt(0) drain is hidden:
//  - R6 lesson: per-lane global->VGPR operand loads expose L2 latency on the
//    wave's critical path (gemm 134us, util 13%). ALL operands go through
//    global_load_lds (fire-and-forget; only the collective barrier waits).
//  - R5 lesson: single-buffered staging exposes the full load latency at
//    every tile barrier (~8000 stall cyc/round). Fix: stage tile t+1 BEFORE
//    computing tile t; the end-of-tile drain then waits on loads that are a
//    whole compute phase old. BK=32 makes the dbuf fit 2 blocks/CU:
//    LDS = 2x32KB (A) + 2x4KB (B) + 2KB = 74KB.
//  - BK=32 keeps 128B LDS rows (the proven conflict-free swizzle) by pairing
//    logical rows: physical row p = logical rows {2p, 2p+1}, 8 slots of 16B,
//    slot s stored at u = s ^ (p&7). Verified: each 8-lane phase group of
//    ds_read_b128 hits 8 distinct slot-columns (same property as R0-R6's
//    measured-zero conflicts).
//  - Apack/BT stored pre-tiled as LDS images (chunk-contiguous staging);
//    K tiles = 9 (288 >= 257) -> 10% less staging+MFMA than LDK=320.

#define NKTOT 17408
#define NBLK 272    // ktiles of 64 k-values
#define NT 9        // K-tiles of 32 (K_eff = 288, cols 257..287 zero)

typedef short bf16x8 __attribute__((ext_vector_type(8)));
typedef float f32x4 __attribute__((ext_vector_type(4)));

__device__ __forceinline__ unsigned short f2bf(float f) {
  unsigned int u = __builtin_bit_cast(unsigned int, f);
  u += 0x7FFFu + ((u >> 16) & 1u);
  return (unsigned short)(u >> 16);
}
__device__ __forceinline__ float bf2f(unsigned int lo16) {
  return __builtin_bit_cast(float, lo16 << 16);
}

__device__ __forceinline__ void async_copy16(void* lds, const void* g) {
  __builtin_amdgcn_global_load_lds(
      (const __attribute__((address_space(1))) unsigned int*)g,
      (__attribute__((address_space(3))) unsigned int*)lds, 16, 0, 0);
}

// Apack image: [c][tt<9][p<256][slot s<8][8 ushorts]
//   content: logical row m = 2p + (s>=4), k-elems j = tt*32 + (s&3)*8 + 0..7
__device__ __forceinline__ size_t aidx(int c, int m, int j) {
  int tt = j >> 5, p = m >> 1;
  int s = ((m & 1) << 2) | ((j >> 3) & 3);
  return ((size_t)((c * 9 + tt) * 256 + p)) * 64 + s * 8 + (j & 7);
}
// BT image: [ktile<272][tt<9][p<32][s<8][8]
//   content: k-col kl = 2p + (s>=4) (within ktile), elems as above
__device__ __forceinline__ size_t bidx(int kt, int kl, int j) {
  int tt = j >> 5, p = kl >> 1;
  int s = ((kl & 1) << 2) | ((j >> 3) & 3);
  return ((size_t)((kt * 9 + tt) * 32 + p)) * 64 + s * 8 + (j & 7);
}

// Fused packing. Blocks 0..1023: fold A (2 (c,a) rows per block).
// Blocks 1024..18431: one k each -> B row (cos|sin) + E1 row.
__global__ __launch_bounds__(256) void pack_all(
    const float* __restrict__ input_r, const float* __restrict__ C_r,
    const float* __restrict__ angle,
    unsigned short* __restrict__ Apack, unsigned short* __restrict__ BT,
    unsigned int* __restrict__ E1tab)
{
  const int bx = blockIdx.x;
  const int tid = threadIdx.x;
  if (bx < 1024) {
    //  XcC[j] = Xc[128+j]+Xc[128-j] (j=1..127), XcC[0]=Xc[128], XcC[128]=Xc[0]
    //  XcS[j] = Xc[128+j]-Xc[128-j] (j=1..127), XcS[128]=-Xc[0]
    //  A_re (rows 0..255)   = [Re XcC | -Im XcS]
    //  A_im (rows 256..511) = [Im XcC |  Re XcS]
    const int p = bx * 2 + (tid >> 7);   // (c,a) pair index 0..2047
    const int a = p & 255;
    const int c = p >> 8;
    const int j = tid & 127;
    const size_t xbase = (size_t)a * 256;
    const size_t cbase = ((size_t)(c * 256 + a)) * 256;
    const int mr = a, mi = 256 + a;
    if (j == 0) {
      float xr = input_r[(xbase + 128) * 2], xi = input_r[(xbase + 128) * 2 + 1];
      float cr = C_r[(cbase + 128) * 2],     ci = C_r[(cbase + 128) * 2 + 1];
      Apack[aidx(c, mr, 0)] = f2bf(cr * xr - ci * xi);
      Apack[aidx(c, mi, 0)] = f2bf(cr * xi + ci * xr);
      xr = input_r[xbase * 2]; xi = input_r[xbase * 2 + 1];
      cr = C_r[cbase * 2];     ci = C_r[cbase * 2 + 1];
      float reb = cr * xr - ci * xi, imb = cr * xi + ci * xr;
      Apack[aidx(c, mr, 128)] = f2bf(reb);    // XcC[128] = Xc(b=0)
      Apack[aidx(c, mi, 128)] = f2bf(imb);
      Apack[aidx(c, mr, 256)] = f2bf(imb);    // -Im(XcS[128])
      Apack[aidx(c, mi, 256)] = f2bf(-reb);   //  Re(XcS[128])
    } else {
      const int bp = 128 + j, bm = 128 - j;
      float xpr = input_r[(xbase + bp) * 2], xpi = input_r[(xbase + bp) * 2 + 1];
      float cpr = C_r[(cbase + bp) * 2],     cpi = C_r[(cbase + bp) * 2 + 1];
      float pr = cpr * xpr - cpi * xpi, pi = cpr * xpi + cpi * xpr;
      float xmr = input_r[(xbase + bm) * 2], xmi = input_r[(xbase + bm) * 2 + 1];
      float cmr = C_r[(cbase + bm) * 2],     cmi = C_r[(cbase + bm) * 2 + 1];
      float mrv = cmr * xmr - cmi * xmi, miv = cmr * xmi + cmi * xmr;
      Apack[aidx(c, mr, j)]       = f2bf(pr + mrv);   //  Re XcC
      Apack[aidx(c, mi, j)]       = f2bf(pi + miv);   //  Im XcC
      Apack[aidx(c, mr, 128 + j)] = f2bf(miv - pi);   // -Im XcS
      Apack[aidx(c, mi, 128 + j)] = f2bf(pr - mrv);   //  Re XcS
    }
    if (j < 31) {  // zero-pad cols 257..287
      Apack[aidx(c, mr, 257 + j)] = 0;
      Apack[aidx(c, mi, 257 + j)] = 0;
    }
  } else {
    const int k = bx - 1024;             // 0..17407
    const int kt = k >> 6, kl = k & 63;
    const float s = angle[k * 2 + 0];
    const float t = angle[k * 2 + 1];
    float sn, cs;
    __sincosf(s * (float)(tid - 128), &sn, &cs);   // E1[k, a=tid]
    E1tab[(size_t)k * 256 + tid] =
        (unsigned int)f2bf(cs) | ((unsigned int)f2bf(sn) << 16);
    if (tid <= 128) {
      __sincosf(t * (float)tid, &sn, &cs);
      BT[bidx(kt, kl, tid)] = f2bf(cs);
      if (tid >= 1) BT[bidx(kt, kl, 128 + tid)] = f2bf(sn);
    } else if (tid < 160) {
      BT[bidx(kt, kl, 128 + tid)] = 0;   // cols 257..287
    }
  }
}

__global__ __launch_bounds__(256, 2) void gemm_fused(
    const unsigned short* __restrict__ Apack,
    const unsigned short* __restrict__ BT,
    const unsigned int* __restrict__ E1tab,
    const float* __restrict__ wvec,
    float* __restrict__ out)
{
  __shared__ unsigned short As[2][16384];  // 2 x 32 KB A double-buffer
  __shared__ unsigned short Bs[2][2048];   // 2 x 4 KB B double-buffer
  __shared__ float scol[4][2][64];         // 2 KB  => 74 KB -> 2 blocks/CU

  // XCD-aware decode: bx%8 == ktile%8 keeps all 8 c-blocks of one ktile on
  // the same XCD. 2176 = 34*64 -> bijective.
  const int bx = blockIdx.x;
  const int c = (bx >> 3) & 7;
  const int ktile = (bx >> 6) * 8 + (bx & 7);   // 0..271
  const int kt0 = ktile * 64;
  const int tid = threadIdx.x;
  const int w = tid >> 6;       // 0..3: owns logical rows w*128..+127
  const int l = tid & 63;
  const int lhi = l >> 4;       // 0..3
  const int llo = l & 15;
  const int lr = l >> 3;                      // staging: phys row within chunk
  const int lsw = ((l & 7) ^ lr) * 8;         // staging: swizzled source slot

  const unsigned short* Aimg = Apack + (size_t)c * 9 * 16384;
  const unsigned short* Bimg = BT + (size_t)ktile * 9 * 2048;

  // fragment read addressing (phys row p, slot u = s ^ (p&7)):
  //   s = (llo&1)*4 + lhi ; p&7 = llo>>1
  const int u8 = (((((llo & 1) << 2) | lhi)) ^ (llo >> 1)) * 8;
  const int aprow = w * 64 + (llo >> 1);
  const int bprow = llo >> 1;

  f32x4 acc[8][4];
#pragma unroll
  for (int i = 0; i < 8; ++i)
#pragma unroll
    for (int j = 0; j < 4; ++j) {
      f32x4 z = {0.f, 0.f, 0.f, 0.f};
      acc[i][j] = z;
    }

  // Prologue: stage tile 0 (A: 8 chunks/wave, B: 1 chunk/wave)
#pragma unroll
  for (int i = 0; i < 8; ++i) {
    int row0 = (w * 8 + i) * 8;
    async_copy16(&As[0][row0 * 64], Aimg + (size_t)(row0 + lr) * 64 + lsw);
  }
  async_copy16(&Bs[0][w * 8 * 64], Bimg + (size_t)(w * 8 + lr) * 64 + lsw);
  __syncthreads();

#pragma unroll 2
  for (int tt = 0; tt < NT; ++tt) {
    const int cu = tt & 1;
    const unsigned short* Ac = As[cu];
    const unsigned short* Bc = Bs[cu];
    // Stage tile tt+1 into the other buffer FIRST (fire-and-forget; the only
    // wait is the end-of-tile __syncthreads, a full compute phase later).
    if (tt < NT - 1) {
      const unsigned short* Asrc = Aimg + (size_t)(tt + 1) * 16384;
      const unsigned short* Bsrc = Bimg + (size_t)(tt + 1) * 2048;
      unsigned short* An = As[cu ^ 1];
      unsigned short* Bn = Bs[cu ^ 1];
#pragma unroll
      for (int i = 0; i < 8; ++i) {
        int row0 = (w * 8 + i) * 8;
        async_copy16(&An[row0 * 64], Asrc + (size_t)(row0 + lr) * 64 + lsw);
      }
      async_copy16(&Bn[w * 8 * 64], Bsrc + (size_t)(w * 8 + lr) * 64 + lsw);
    }
    __builtin_amdgcn_sched_barrier(0);   // staging issue stays above compute

    bf16x8 bfr[4];
#pragma unroll
    for (int fj = 0; fj < 4; ++fj)
      bfr[fj] = *(const bf16x8*)&Bc[(fj * 8 + bprow) * 64 + u8];
    bf16x8 af[8];
#pragma unroll
    for (int fi = 0; fi < 8; ++fi)
      af[fi] = *(const bf16x8*)&Ac[(aprow + fi * 8) * 64 + u8];
#pragma unroll
    for (int fi = 0; fi < 8; ++fi)
#pragma unroll
      for (int fj = 0; fj < 4; ++fj)
        acc[fi][fj] = __builtin_amdgcn_mfma_f32_16x16x32_bf16(
            af[fi], bfr[fj], acc[fi][fj], 0, 0, 0);
    // Tile end: vmcnt(0)+lgkmcnt(0)+barrier — stages are ~44 instrs old.
    __syncthreads();
  }

  // Epilogue: wave w holds T rows (w<2: Tr, w>=2: Ti), a-half = (w&1)*128.
  // Per col: S_r = sum E1r*v, S_i = sum E1i*v over this wave's 128 rows.
  const int ahalf = (w & 1) * 128;
#pragma unroll
  for (int fj = 0; fj < 4; ++fj) {
    const int col = fj * 16 + llo;
    const int k = kt0 + col;
    float sumr = 0.f, sumi = 0.f;
    const unsigned int* e1base = E1tab + (size_t)k * 256 + ahalf + lhi * 4;
#pragma unroll
    for (int fi = 0; fi < 8; ++fi) {
      uint4 e4 = *(const uint4*)(e1base + fi * 16);
      unsigned int ev[4] = {e4.x, e4.y, e4.z, e4.w};
#pragma unroll
      for (int r = 0; r < 4; ++r) {
        float v = acc[fi][fj][r];     // T at (a = ahalf + fi*16 + lhi*4 + r, k)
        sumr += bf2f(ev[r] & 0xFFFFu) * v;
        sumi += bf2f(ev[r] >> 16) * v;
      }
    }
    sumr += __shfl_xor(sumr, 16, 64);
    sumr += __shfl_xor(sumr, 32, 64);
    sumi += __shfl_xor(sumi, 16, 64);
    sumi += __shfl_xor(sumi, 32, 64);
    if (lhi == 0) {
      scol[w][0][col] = sumr;
      scol[w][1][col] = sumi;
    }
  }
  __syncthreads();
  if (tid < 128) {
    const int col = tid >> 1;
    const int comp = tid & 1;
    const int k = kt0 + col;
    // Re = S_rr(w0)+S_rr(w1) - S_ii(w2)-S_ii(w3)
    // Im = S_ri(w0)+S_ri(w1) + S_ir(w2)+S_ir(w3)
    float re = scol[0][0][col] + scol[1][0][col]
             - scol[2][1][col] - scol[3][1][col];
    float im = scol[0][1][col] + scol[1][1][col]
             + scol[2][0][col] + scol[3][0][col];
    float val = comp ? im : re;
    out[((size_t)c * NKTOT + k) * 2 + comp] = val * wvec[k & 511];
  }
}

extern "C" void kernel_launch(void* const* d_in, const int* in_sizes, int n_in,
                              void* d_out, int out_size, void* d_ws, size_t ws_size,
                              hipStream_t stream) {
  const float* input_r = (const float*)d_in[0];  // (256,256,2)
  const float* C_r     = (const float*)d_in[1];  // (8,256,256,2)
  const float* wvec    = (const float*)d_in[2];  // (512,)
  const float* angle   = (const float*)d_in[3];  // (17408,2)
  float* out = (float*)d_out;                    // (8,17408,2)

  // workspace: Apack 8*9*32KB = 2.25MB | BT 272*9*4KB = 9.56MB |
  //            E1tab 17408*256*4 = 17.8MB  => ~29.6MB
  unsigned short* Apack = (unsigned short*)d_ws;
  unsigned short* BT    = (unsigned short*)((char*)d_ws + (size_t)2359296);
  unsigned int*   E1tab = (unsigned int*)((char*)d_ws + (size_t)2359296 + 10027008);

  pack_all<<<1024 + NKTOT, 256, 0, stream>>>(input_r, C_r, angle,
                                             Apack, BT, E1tab);
  gemm_fused<<<8 * NBLK, 256, 0, stream>>>(Apack, BT, E1tab, wvec, out);
}